// Round 9
// baseline (368.004 us; speedup 1.0000x reference)
//
#include <hip/hip_runtime.h>
#include <math.h>

#define N_B 16
#define T_LEN 4096

typedef float f32x4  __attribute__((ext_vector_type(4)));
typedef _Float16 half8 __attribute__((ext_vector_type(8)));

// ---- workspace layout (float offsets) ----
static const size_t OFF_A    = 0;            // 16*128*4096
static const size_t OFF_B    = 8388608;      // 16*256*4096
static const size_t OFF_Z    = 25165824;     // 16*64*4096 (q destination)
static const size_t OFF_WS   = 29360128;     // split-weight region
static const size_t OFF_CBS  = 29540352;     // codebook split (32768 floats)
static const size_t OFF_C2   = 29683712;
static const size_t OFF_ST   = 29684736;
static const size_t OFF_LOSS = 29685760;

// split-weight offsets (floats from OFF_WS); decoder reuses after zvq_k
static const size_t WS_E1 = 0;        // 3*3*128*32 = 36864 floats
static const size_t WS_E2 = 36864;    // 4*3*256*32 = 98304 floats
static const size_t WS_E3 = 135168;   // 8*1*64*32  = 16384 floats -> 151552
static const size_t WS_D1 = 0;        // 2*3*256*32 = 49152 floats
static const size_t WS_D2 = 49152;    // 8*3*128*32 = 98304 floats
static const size_t WS_D3 = 147456;   // 4*3*80*32  = 30720 floats -> 178176

// scaled f16 split: v = hi + lo * 2^-12, error ~2^-24 relative (f32-grade).
__device__ inline void f2h2(float v, short& hi, short& lo) {
    _Float16 h = (_Float16)v;
    float r = (v - (float)h) * 4096.0f;
    _Float16 l = (_Float16)r;
    hi = __builtin_bit_cast(short, h);
    lo = __builtin_bit_cast(short, l);
}
__device__ inline float h2f(short s) {
    return (float)__builtin_bit_cast(_Float16, s);
}

// fill split-weight fragments: dst layout [(c*KS+k)*2+p][co][32 ci-shorts]
template<int C_IN, int C_OUT, int KS>
__device__ inline void wsplit_fill(const float* __restrict__ w,
                                   short* __restrict__ dst, int e) {
    int i  = e & 31;
    int r  = e >> 5;
    int co = r % C_OUT;
    int r2 = r / C_OUT;          // c*KS + k
    int k  = r2 % KS;
    int c  = r2 / KS;
    int ci = c * 32 + i;
    float v = (ci < C_IN) ? w[((size_t)co * C_IN + ci) * KS + k] : 0.f;
    short h, l; f2h2(v, h, l);
    size_t base = ((size_t)(c * KS + k) * 2 * C_OUT + co) * 32 + i;
    dst[base] = h;
    dst[base + (size_t)C_OUT * 32] = l;
}

__global__ __launch_bounds__(256) void prep_k(
        const float* __restrict__ w1, const float* __restrict__ w2,
        const float* __restrict__ w3, const float* __restrict__ cb,
        float* wsf) {
    int e = blockIdx.x * 256 + threadIdx.x;
    if (e < 36864)        wsplit_fill<80, 128, 3>(w1, (short*)(wsf + OFF_WS + WS_E1), e);
    else if (e < 135168)  wsplit_fill<128, 256, 3>(w2, (short*)(wsf + OFF_WS + WS_E2), e - 36864);
    else if (e < 151552)  wsplit_fill<256, 64, 1>(w3, (short*)(wsf + OFF_WS + WS_E3), e - 135168);
    else if (e < 152064) {
        int c = e - 151552;
        const float* p = cb + (size_t)c * 64;
        double s = 0.0;
        for (int d = 0; d < 64; ++d) { double v = p[d]; s += v * v; }
        wsf[OFF_C2 + c] = (float)s;
    } else if (e < 184832) {
        // codebook split fragments (zvq_k): [ks][plane][code][32 d-shorts]
        int e2   = e - 152064;
        int i    = e2 & 31;
        int r    = e2 >> 5;
        int code = r & 511;
        int ks   = r >> 9;
        float v  = cb[(size_t)code * 64 + ks * 32 + i];
        short h, l; f2h2(v, h, l);
        short* dst = (short*)(wsf + OFF_CBS);
        dst[((size_t)(ks * 2 + 0) * 512 + code) * 32 + i] = h;
        dst[((size_t)(ks * 2 + 1) * 512 + code) * 32 + i] = l;
    } else if (e == 184832) {
        *(double*)(wsf + OFF_LOSS) = 0.0;
    }
}

__global__ __launch_bounds__(256) void prep2_k(
        const float* __restrict__ wd1, const float* __restrict__ wd2,
        const float* __restrict__ wd3, float* wsf) {
    int e = blockIdx.x * 256 + threadIdx.x;
    if (e < 49152)        wsplit_fill<64, 256, 3>(wd1, (short*)(wsf + OFF_WS + WS_D1), e);
    else if (e < 147456)  wsplit_fill<256, 128, 3>(wd2, (short*)(wsf + OFF_WS + WS_D2), e - 49152);
    else if (e < 178176)  wsplit_fill<128, 80, 3>(wd3, (short*)(wsf + OFF_WS + WS_D3), e - 147456);
}

// ---- conv1d via scaled-f16 split MFMA (r8 8-wave chassis, KS=3 only) ----
// Block: 512 thr = 8 waves, CO_TILE=128 (8 co-strips x full TT=128).
// Maps (HW-verified r1-r8): A[m=lane&15][k=q*8+j], B[k=q*8+j][n=lane&15],
// D[m=q*4+r][n=lane&15].  acc0 += ah*bh ; acc1 += ah*bl + al*bh.
template<int C_IN, int C_OUT, int KS, bool BN_IN, bool STATS>
__global__ __launch_bounds__(512, 4) void fconv_k(
        const float* __restrict__ x, const short* __restrict__ wsp,
        const float* __restrict__ bias, const float2* __restrict__ stats,
        float* __restrict__ out, float2* __restrict__ part) {
    constexpr int NCH  = (C_IN + 31) / 32;
    constexpr int HALO = KS / 2;
    constexpr int TT   = (KS == 1) ? 64 : 128;   // t-tile
    constexpr int WT   = (KS == 1) ? 2 : 1;      // waves along t
    constexpr int WCO  = 8 / WT;                 // waves along co
    constexpr int HT   = TT / WT;                // t per wave
    constexpr int NTT  = HT / 16;                // MFMA t-subtiles per wave
    constexpr int NTILE = T_LEN / TT;
    constexpr int XR   = TT + KS - 1;
    constexpr int RS   = 72;                     // shorts/row (144B, 16B-aligned)
    constexpr int LO   = 40;                     // lo-plane offset within row
    constexpr int TQ   = TT / 4;                 // t-stride for 4-way load

    __shared__ __align__(16) short xs[XR * RS];

    const int tid  = threadIdx.x;
    const int lane = tid & 63;
    const int wv   = tid >> 6;
    const int wvc  = wv % WCO;                   // co strip
    const int wvt  = wv / WCO;                   // t half (KS==1 only)
    const int ln   = lane & 15;
    const int q    = lane >> 4;

    const int n    = blockIdx.x / NTILE;
    const int t0   = (blockIdx.x % NTILE) * TT;
    const int co0  = blockIdx.y * (WCO * 16);
    const int co_l = co0 + wvc * 16 + ln;        // A-fragment row for this lane

    f32x4 a0[NTT], a1[NTT];
#pragma unroll
    for (int tt = 0; tt < NTT; ++tt)
#pragma unroll
        for (int i = 0; i < 4; ++i) { a0[tt][i] = 0.f; a1[tt][i] = 0.f; }

#pragma unroll 1
    for (int c = 0; c < NCH; ++c) {
        // ---- w fragments: direct global loads (L2-hot, coalesced 16B) ----
        half8 ah[KS], al[KS];
        {
            half8 z = {0, 0, 0, 0, 0, 0, 0, 0};
#pragma unroll
            for (int k = 0; k < KS; ++k) {
                const short* wp = wsp
                    + ((size_t)(c * KS + k) * 2 * C_OUT + co_l) * 32 + q * 8;
                ah[k] = (co_l < C_OUT) ? *(const half8*)wp : z;
                al[k] = (co_l < C_OUT) ? *(const half8*)(wp + (size_t)C_OUT * 32) : z;
            }
        }

        __syncthreads();
        // ---- stage x tile [t-row][ci] with split planes ----
        for (int e = tid; e < 32 * TQ; e += 512) {
            const int ci  = e / TQ;
            const int tq  = e % TQ;
            const int cig = c * 32 + ci;
            float v[4] = {0.f, 0.f, 0.f, 0.f};
            if (cig < C_IN) {
                const float* xp = x + ((size_t)(n * C_IN + cig)) * T_LEN + t0 + tq;
#pragma unroll
                for (int j = 0; j < 4; ++j) v[j] = xp[TQ * j];
                if (BN_IN) {
                    float2 s = stats[cig];
#pragma unroll
                    for (int j = 0; j < 4; ++j) v[j] = fmaxf(fmaf(v[j], s.x, s.y), 0.f);
                }
            }
#pragma unroll
            for (int j = 0; j < 4; ++j) {
                short h, l; f2h2(v[j], h, l);
                short* p = &xs[(HALO + tq + TQ * j) * RS + ci];
                p[0]  = h;
                p[LO] = l;
            }
        }
        if (KS == 3) {
            if (tid < 64) {
                const int ci   = tid & 31;
                const int side = tid >> 5;
                const int cig  = c * 32 + ci;
                const int gt   = side ? (t0 + TT) : (t0 - 1);
                float v = 0.f;
                if (cig < C_IN && gt >= 0 && gt < T_LEN) {
                    v = x[((size_t)(n * C_IN + cig)) * T_LEN + gt];
                    if (BN_IN) {
                        float2 s = stats[cig];
                        v = fmaxf(fmaf(v, s.x, s.y), 0.f);
                    }
                }
                short h, l; f2h2(v, h, l);
                short* p = &xs[(side ? (XR - 1) : 0) * RS + ci];
                p[0] = h; p[LO] = l;
            }
        }
        __syncthreads();

        // ---- MFMA: 3-product split (b128 LDS reads) ----
#pragma unroll
        for (int k = 0; k < KS; ++k) {
#pragma unroll
            for (int tt = 0; tt < NTT; ++tt) {
                const short* xr = &xs[(wvt * HT + tt * 16 + ln + k) * RS + q * 8];
                half8 bh = *(const half8*)&xr[0];
                half8 bl = *(const half8*)&xr[LO];
                a0[tt] = __builtin_amdgcn_mfma_f32_16x16x32_f16(ah[k], bh, a0[tt], 0, 0, 0);
                a1[tt] = __builtin_amdgcn_mfma_f32_16x16x32_f16(ah[k], bl, a1[tt], 0, 0, 0);
                a1[tt] = __builtin_amdgcn_mfma_f32_16x16x32_f16(al[k], bh, a1[tt], 0, 0, 0);
            }
        }
    }

    // epilogue: lane reg r -> D[co = co0+wvc*16+q*4+r][t = t0+wvt*HT+tt*16+ln]
    const int plinear = blockIdx.y * (N_B * NTILE) + blockIdx.x;
#pragma unroll
    for (int r = 0; r < 4; ++r) {
        const int co = co0 + wvc * 16 + q * 4 + r;
        float s1 = 0.f, s2 = 0.f;
        if (co < C_OUT) {
            const float bv = bias[co];
            float* op = out + ((size_t)(n * C_OUT + co)) * T_LEN + t0 + wvt * HT + ln;
#pragma unroll
            for (int tt = 0; tt < NTT; ++tt) {
                const float v = fmaf(a1[tt][r], 0.000244140625f, a0[tt][r]) + bv;
                op[tt * 16] = v;
                if (STATS) { s1 += v; s2 = fmaf(v, v, s2); }
            }
        }
        if (STATS) {
#pragma unroll
            for (int off = 1; off <= 8; off <<= 1) {
                s1 += __shfl_xor(s1, off);
                s2 += __shfl_xor(s2, off);
            }
            if (ln == 0)
                part[(size_t)plinear * 128 + wvc * 16 + q * 4 + r] =
                    make_float2(s1, s2);
        }
    }
}

// ---- BN stats: reduce 512 per-block float2 partials per channel (f64) ----
__global__ __launch_bounds__(256) void stats_k(
        const float2* __restrict__ part, const float* __restrict__ g,
        const float* __restrict__ b, float2* __restrict__ stats) {
    const int c = blockIdx.x;
    const int tid = threadIdx.x;
    double s1 = 0.0, s2 = 0.0;
    for (int j = tid; j < 512; j += 256) {
        float2 v = part[((size_t)(c >> 7) * 512 + j) * 128 + (c & 127)];
        s1 += (double)v.x; s2 += (double)v.y;
    }
    __shared__ double r1[256], r2[256];
    r1[tid] = s1; r2[tid] = s2;
    __syncthreads();
    for (int s = 128; s > 0; s >>= 1) {
        if (tid < s) { r1[tid] += r1[tid + s]; r2[tid] += r2[tid + s]; }
        __syncthreads();
    }
    if (tid == 0) {
        double m   = r1[0] / 65536.0;
        double var = r2[0] / 65536.0 - m * m;
        double sc  = (double)g[c] / sqrt(var + 1e-5);
        stats[c] = make_float2((float)sc, (float)((double)b[c] - m * sc));
    }
}

// ---- fused enc3 (1x1 conv) + VQ: z never touches HBM ----
// Conv part: exact r8 enc3 structure (KS=1, TT=64, WCO=4, WT=2) -> z in regs,
// written to LDS (f32 + split planes). VQ part: identical score formula;
// waves (wv, wv+4) split the 32 code-tiles 16/16 (argmin+lowest-idx tie-break
// is partition-invariant), merge via LDS.
__global__ __launch_bounds__(512, 4) void zvq_k(
        const float* __restrict__ x, const short* __restrict__ wsp,
        const float* __restrict__ bias, const float2* __restrict__ stats,
        const float* __restrict__ cb, const short* __restrict__ cbs,
        const float* __restrict__ c2, float* __restrict__ q,
        float* __restrict__ idx_out, double* __restrict__ loss) {
    constexpr int RS = 72, LO = 40;

    __shared__ __align__(16) short xs[64 * RS];
    __shared__ __align__(16) float zs[64 * 68];
    __shared__ __align__(16) short zh[64 * 136];
    __shared__ float  c2s[512];
    __shared__ float  szf_s[64];
    __shared__ float  redS[64 * 2];
    __shared__ int    redI[64 * 2];
    __shared__ int    idxs[64];
    __shared__ double dred[512];

    const int tid  = threadIdx.x;
    const int lane = tid & 63;
    const int wv   = tid >> 6;
    const int wvc  = wv & 3;       // co strip (conv phase)
    const int wvt  = wv >> 2;      // t half (conv phase)
    const int ln   = lane & 15;
    const int qq   = lane >> 4;
    const int n    = blockIdx.x >> 6;
    const int t0   = (blockIdx.x & 63) * 64;
    const int co_l = wvc * 16 + ln;

    for (int e = tid; e < 512; e += 512) c2s[e] = c2[e];

    // ---- conv phase: z = conv1x1(relu(bn(x))) + bias (r8-identical order) ----
    f32x4 a0[2], a1[2];
#pragma unroll
    for (int tt = 0; tt < 2; ++tt)
#pragma unroll
        for (int i = 0; i < 4; ++i) { a0[tt][i] = 0.f; a1[tt][i] = 0.f; }

#pragma unroll 1
    for (int c = 0; c < 8; ++c) {
        half8 ah, al;
        {
            const short* wp = wsp + ((size_t)c * 2 * 64 + co_l) * 32 + qq * 8;
            ah = *(const half8*)wp;
            al = *(const half8*)(wp + (size_t)64 * 32);
        }
        __syncthreads();
        {
            const int ci  = tid >> 4;        // 32 ci x 16 tq = 512 threads
            const int tq  = tid & 15;
            const int cig = c * 32 + ci;
            const float* xp = x + ((size_t)(n * 256 + cig)) * T_LEN + t0 + tq;
            const float2 s = stats[cig];
#pragma unroll
            for (int j = 0; j < 4; ++j) {
                const float v = fmaxf(fmaf(xp[16 * j], s.x, s.y), 0.f);
                short h, l; f2h2(v, h, l);
                short* p = &xs[(tq + 16 * j) * RS + ci];
                p[0]  = h;
                p[LO] = l;
            }
        }
        __syncthreads();
#pragma unroll
        for (int tt = 0; tt < 2; ++tt) {
            const short* xr = &xs[(wvt * 32 + tt * 16 + ln) * RS + qq * 8];
            half8 bh = *(const half8*)&xr[0];
            half8 bl = *(const half8*)&xr[LO];
            a0[tt] = __builtin_amdgcn_mfma_f32_16x16x32_f16(ah, bh, a0[tt], 0, 0, 0);
            a1[tt] = __builtin_amdgcn_mfma_f32_16x16x32_f16(ah, bl, a1[tt], 0, 0, 0);
            a1[tt] = __builtin_amdgcn_mfma_f32_16x16x32_f16(al, bh, a1[tt], 0, 0, 0);
        }
    }
    __syncthreads();
    // epilogue -> LDS only: zs (f32) + zh (split planes, vq fragment layout)
#pragma unroll
    for (int r = 0; r < 4; ++r) {
        const int d  = wvc * 16 + qq * 4 + r;
        const float bv = bias[d];
        const int ks = d >> 5, i = d & 31;
#pragma unroll
        for (int tt = 0; tt < 2; ++tt) {
            const int t = wvt * 32 + tt * 16 + ln;
            const float v = fmaf(a1[tt][r], 0.000244140625f, a0[tt][r]) + bv;
            zs[t * 68 + d] = v;
            short h, l; f2h2(v, h, l);
            zh[t * 136 + (ks * 2 + 0) * 32 + i] = h;
            zh[t * 136 + (ks * 2 + 1) * 32 + i] = l;
        }
    }
    __syncthreads();
    if (tid < 64) {
        double s = 0.0;
        const float* zr = &zs[tid * 68];
        for (int d = 0; d < 64; ++d) { double v = zr[d]; s += v * v; }
        szf_s[tid] = (float)s;
    }
    __syncthreads();

    // ---- VQ sweep: wave pair (wv, wv+4) splits 32 code-tiles 16/16 ----
    const int tl   = (wv & 3) * 16 + ln;
    const int half = wv >> 2;
    const short* zr = &zh[tl * 136 + qq * 8];
    const half8 bh0 = *(const half8*)&zr[0];
    const half8 bl0 = *(const half8*)&zr[32];
    const half8 bh1 = *(const half8*)&zr[64];
    const half8 bl1 = *(const half8*)&zr[96];
    const float As  = szf_s[tl];

    float bs = 3.0e38f;
    int   bi = 1 << 30;

#pragma unroll 4
    for (int ct = half * 16; ct < half * 16 + 16; ++ct) {
        const short* ap = cbs + ((size_t)(ct * 16 + ln)) * 32 + qq * 8;
        const half8 ah0 = *(const half8*)&ap[0];
        const half8 al0 = *(const half8*)&ap[512 * 32];
        const half8 ah1 = *(const half8*)&ap[2 * 512 * 32];
        const half8 al1 = *(const half8*)&ap[3 * 512 * 32];
        f32x4 p0 = {0.f, 0.f, 0.f, 0.f};
        f32x4 p1 = {0.f, 0.f, 0.f, 0.f};
        p0 = __builtin_amdgcn_mfma_f32_16x16x32_f16(ah0, bh0, p0, 0, 0, 0);
        p1 = __builtin_amdgcn_mfma_f32_16x16x32_f16(ah0, bl0, p1, 0, 0, 0);
        p1 = __builtin_amdgcn_mfma_f32_16x16x32_f16(al0, bh0, p1, 0, 0, 0);
        p0 = __builtin_amdgcn_mfma_f32_16x16x32_f16(ah1, bh1, p0, 0, 0, 0);
        p1 = __builtin_amdgcn_mfma_f32_16x16x32_f16(ah1, bl1, p1, 0, 0, 0);
        p1 = __builtin_amdgcn_mfma_f32_16x16x32_f16(al1, bh1, p1, 0, 0, 0);
#pragma unroll
        for (int r = 0; r < 4; ++r) {
            const int code = ct * 16 + qq * 4 + r;
            const float m32 = fmaf(p1[r], 0.000244140625f, p0[r]);
            const float A   = As + c2s[code];
            const float s   = A - 2.0f * m32;
            if (s < bs || (s == bs && code < bi)) { bs = s; bi = code; }
        }
    }
#pragma unroll
    for (int off = 16; off <= 32; off <<= 1) {
        const float os = __shfl_xor(bs, off);
        const int   oi = __shfl_xor(bi, off);
        if (os < bs || (os == bs && oi < bi)) { bs = os; bi = oi; }
    }
    if (qq == 0) { redS[tl * 2 + half] = bs; redI[tl * 2 + half] = bi; }
    __syncthreads();
    if (tid < 64) {
        const int t = tid;
        float b0 = redS[t * 2], b1v = redS[t * 2 + 1];
        int   i0 = redI[t * 2], i1v = redI[t * 2 + 1];
        int bi2; float bs2;
        if (b1v < b0 || (b1v == b0 && i1v < i0)) { bs2 = b1v; bi2 = i1v; }
        else { bs2 = b0; bi2 = i0; }
        (void)bs2;
        idxs[t] = bi2;
        idx_out[(size_t)n * T_LEN + t0 + t] = (float)bi2;
    }
    __syncthreads();

    // ---- quantized write + loss (f64 exact) ----
    {
        const int g = tid >> 6, t = tid & 63;
        const int bi2 = idxs[t];
        double ls = 0.0;
        for (int dd = 0; dd < 8; ++dd) {
            const int d = g * 8 + dd;
            const float qv = cb[(size_t)bi2 * 64 + d];
            const float zv = zs[t * 68 + d];
            const double df = (double)qv - (double)zv;
            ls += df * df;
            q[((size_t)(n * 64 + d)) * T_LEN + t0 + t] = qv;
        }
        dred[tid] = ls;
    }
    __syncthreads();
    for (int s = 256; s > 0; s >>= 1) {
        if (tid < s) dred[tid] += dred[tid + s];
        __syncthreads();
    }
    if (tid == 0) atomicAdd(loss, dred[0]);
}

__global__ void fin_k(const double* __restrict__ loss, float* __restrict__ out) {
    if (threadIdx.x == 0 && blockIdx.x == 0)
        out[0] = (float)(1.25 * (*loss) / 4194304.0);
}

extern "C" void kernel_launch(void* const* d_in, const int* in_sizes, int n_in,
                              void* d_out, int out_size, void* d_ws, size_t ws_size,
                              hipStream_t stream) {
    const float* x      = (const float*)d_in[0];
    const float* enc_w1 = (const float*)d_in[1];
    const float* enc_b1 = (const float*)d_in[2];
    const float* bn1_g  = (const float*)d_in[3];
    const float* bn1_b  = (const float*)d_in[4];
    const float* enc_w2 = (const float*)d_in[5];
    const float* enc_b2 = (const float*)d_in[6];
    const float* bn2_g  = (const float*)d_in[7];
    const float* bn2_b  = (const float*)d_in[8];
    const float* enc_w3 = (const float*)d_in[9];
    const float* enc_b3 = (const float*)d_in[10];
    const float* cb     = (const float*)d_in[11];
    const float* dec_w1 = (const float*)d_in[12];
    const float* dec_b1 = (const float*)d_in[13];
    const float* dbn1_g = (const float*)d_in[14];
    const float* dbn1_b = (const float*)d_in[15];
    const float* dec_w2 = (const float*)d_in[16];
    const float* dec_b2 = (const float*)d_in[17];
    const float* dbn2_g = (const float*)d_in[18];
    const float* dbn2_b = (const float*)d_in[19];
    const float* dec_w3 = (const float*)d_in[20];
    const float* dec_b3 = (const float*)d_in[21];

    float* wsf   = (float*)d_ws;
    float* outf  = (float*)d_out;
    float* A     = wsf + OFF_A;
    float* Bb    = wsf + OFF_B;
    float* Z     = wsf + OFF_Z;
    float2* st   = (float2*)(wsf + OFF_ST);
    double* lossp = (double*)(wsf + OFF_LOSS);

    const short* wsE1 = (const short*)(wsf + OFF_WS + WS_E1);
    const short* wsE2 = (const short*)(wsf + OFF_WS + WS_E2);
    const short* wsE3 = (const short*)(wsf + OFF_WS + WS_E3);
    const short* wsD1 = (const short*)(wsf + OFF_WS + WS_D1);
    const short* wsD2 = (const short*)(wsf + OFF_WS + WS_D2);
    const short* wsD3 = (const short*)(wsf + OFF_WS + WS_D3);
    const short* cbs  = (const short*)(wsf + OFF_CBS);

    // partial-stat buffers live in whichever big buffer is dead at that stage
    float2* pE1 = (float2*)Bb;   // enc1: Bb free until enc2 writes it
    float2* pE2 = (float2*)Z;    // enc2: Z free until zvq writes q into it
    float2* pD1 = (float2*)A;    // dec1: A free until dec2 writes it
    float2* pD2 = (float2*)(wsf + OFF_B + 4194304); // dec2: upper half of Bb (dead)

    prep_k<<<723, 256, 0, stream>>>(enc_w1, enc_w2, enc_w3, cb, wsf);

    // encoder — 8-wave blocks, CO_TILE=128
    fconv_k<80, 128, 3, false, true><<<dim3(512, 1), 512, 0, stream>>>(
        x, wsE1, enc_b1, nullptr, A, pE1);
    stats_k<<<128, 256, 0, stream>>>(pE1, bn1_g, bn1_b, st);
    fconv_k<128, 256, 3, true, true><<<dim3(512, 2), 512, 0, stream>>>(
        A, wsE2, enc_b2, st, Bb, pE2);
    stats_k<<<256, 256, 0, stream>>>(pE2, bn2_g, bn2_b, st);

    // fused enc3 + VQ (z stays in LDS; q written into Z region)
    zvq_k<<<1024, 512, 0, stream>>>(Bb, wsE3, enc_b3, st, cb, cbs,
                                    wsf + OFF_C2, Z, outf + 5242881, lossp);
    fin_k<<<1, 64, 0, stream>>>(lossp, outf + 5242880);

    // decoder splits overwrite (now-dead) encoder splits
    prep2_k<<<696, 256, 0, stream>>>(dec_w1, dec_w2, dec_w3, wsf);

    // decoder
    fconv_k<64, 256, 3, false, true><<<dim3(512, 2), 512, 0, stream>>>(
        Z, wsD1, dec_b1, nullptr, Bb, pD1);
    stats_k<<<256, 256, 0, stream>>>(pD1, dbn1_g, dbn1_b, st);
    fconv_k<256, 128, 3, true, true><<<dim3(512, 1), 512, 0, stream>>>(
        Bb, wsD2, dec_b2, st, A, pD2);
    stats_k<<<128, 256, 0, stream>>>(pD2, dbn2_g, dbn2_b, st);
    fconv_k<128, 80, 3, true, false><<<dim3(512, 1), 512, 0, stream>>>(
        A, wsD3, dec_b3, st, outf, nullptr);
}

// Round 10
// 364.224 us; speedup vs baseline: 1.0104x; 1.0104x over previous
//
#include <hip/hip_runtime.h>
#include <math.h>

#define N_B 16
#define T_LEN 4096

typedef float f32x4  __attribute__((ext_vector_type(4)));
typedef _Float16 half8 __attribute__((ext_vector_type(8)));

// ---- workspace layout (float offsets) ----
static const size_t OFF_A    = 0;            // 16*128*4096
static const size_t OFF_B    = 8388608;      // 16*256*4096
static const size_t OFF_Z    = 25165824;     // 16*64*4096
static const size_t OFF_WS   = 29360128;     // split-weight region
static const size_t OFF_CBS  = 29540352;     // codebook split (32768 floats)
static const size_t OFF_C2   = 29683712;
static const size_t OFF_ST   = 29684736;
static const size_t OFF_LOSS = 29685760;

// split-weight offsets (floats from OFF_WS); decoder reuses after enc convs
static const size_t WS_E1 = 0;        // 3*3*128*32 = 36864 floats
static const size_t WS_E2 = 36864;    // 4*3*256*32 = 98304 floats
static const size_t WS_E3 = 135168;   // 8*1*64*32  = 16384 floats -> 151552
static const size_t WS_D1 = 0;        // 2*3*256*32 = 49152 floats
static const size_t WS_D2 = 49152;    // 8*3*128*32 = 98304 floats
static const size_t WS_D3 = 147456;   // 4*3*80*32  = 30720 floats -> 178176

// scaled f16 split: v = hi + lo * 2^-12, error ~2^-24 relative (f32-grade).
__device__ inline void f2h2(float v, short& hi, short& lo) {
    _Float16 h = (_Float16)v;
    float r = (v - (float)h) * 4096.0f;
    _Float16 l = (_Float16)r;
    hi = __builtin_bit_cast(short, h);
    lo = __builtin_bit_cast(short, l);
}
__device__ inline float h2f(short s) {
    return (float)__builtin_bit_cast(_Float16, s);
}

// fill split-weight fragments: dst layout [(c*KS+k)*2+p][co][32 ci-shorts]
template<int C_IN, int C_OUT, int KS>
__device__ inline void wsplit_fill(const float* __restrict__ w,
                                   short* __restrict__ dst, int e) {
    int i  = e & 31;
    int r  = e >> 5;
    int co = r % C_OUT;
    int r2 = r / C_OUT;          // c*KS + k
    int k  = r2 % KS;
    int c  = r2 / KS;
    int ci = c * 32 + i;
    float v = (ci < C_IN) ? w[((size_t)co * C_IN + ci) * KS + k] : 0.f;
    short h, l; f2h2(v, h, l);
    size_t base = ((size_t)(c * KS + k) * 2 * C_OUT + co) * 32 + i;
    dst[base] = h;
    dst[base + (size_t)C_OUT * 32] = l;
}

__global__ __launch_bounds__(256) void prep_k(
        const float* __restrict__ w1, const float* __restrict__ w2,
        const float* __restrict__ w3, const float* __restrict__ cb,
        float* wsf) {
    int e = blockIdx.x * 256 + threadIdx.x;
    if (e < 36864)        wsplit_fill<80, 128, 3>(w1, (short*)(wsf + OFF_WS + WS_E1), e);
    else if (e < 135168)  wsplit_fill<128, 256, 3>(w2, (short*)(wsf + OFF_WS + WS_E2), e - 36864);
    else if (e < 151552)  wsplit_fill<256, 64, 1>(w3, (short*)(wsf + OFF_WS + WS_E3), e - 135168);
    else if (e < 152064) {
        int c = e - 151552;
        const float* p = cb + (size_t)c * 64;
        double s = 0.0;
        for (int d = 0; d < 64; ++d) { double v = p[d]; s += v * v; }
        wsf[OFF_C2 + c] = (float)s;
    } else if (e < 184832) {
        // codebook split fragments (vq_k): [ks][plane][code][32 d-shorts]
        int e2   = e - 152064;
        int i    = e2 & 31;
        int r    = e2 >> 5;
        int code = r & 511;
        int ks   = r >> 9;
        float v  = cb[(size_t)code * 64 + ks * 32 + i];
        short h, l; f2h2(v, h, l);
        short* dst = (short*)(wsf + OFF_CBS);
        dst[((size_t)(ks * 2 + 0) * 512 + code) * 32 + i] = h;
        dst[((size_t)(ks * 2 + 1) * 512 + code) * 32 + i] = l;
    } else if (e == 184832) {
        *(double*)(wsf + OFF_LOSS) = 0.0;
    }
}

__global__ __launch_bounds__(256) void prep2_k(
        const float* __restrict__ wd1, const float* __restrict__ wd2,
        const float* __restrict__ wd3, float* wsf) {
    int e = blockIdx.x * 256 + threadIdx.x;
    if (e < 49152)        wsplit_fill<64, 256, 3>(wd1, (short*)(wsf + OFF_WS + WS_D1), e);
    else if (e < 147456)  wsplit_fill<256, 128, 3>(wd2, (short*)(wsf + OFF_WS + WS_D2), e - 49152);
    else if (e < 178176)  wsplit_fill<128, 80, 3>(wd3, (short*)(wsf + OFF_WS + WS_D3), e - 147456);
}

// ---- conv1d via scaled-f16 split MFMA (r8 8-wave chassis + T3 2-phase) ----
// Block: 512 thr = 8 waves. KS=3: CO_TILE=128, TT=128. KS=1: CO_TILE=64, TT=128
// (2 t-halves). Double-buffered LDS, ONE barrier per ci-chunk: prologue stages
// chunk 0; each iter {barrier; stage(next->other buf); MFMA(current buf)} —
// staging's global loads/ds_writes drain at the NEXT barrier, i.e. they fly
// under the MFMA phase (T3 minimum 2-phase; race-safe: a wave passes barrier
// c+1 only after its chunk-c MFMA reads, so restaging buf c&1 is ordered).
// Maps (HW-verified r1-r9): A[m=lane&15][k=q*8+j], B[k=q*8+j][n=lane&15],
// D[m=q*4+r][n=lane&15].  acc0 += ah*bh ; acc1 += ah*bl + al*bh.
// Per-output MFMA accumulation order identical to r8 -> bitwise-same conv out.
template<int C_IN, int C_OUT, int KS, bool BN_IN, bool STATS>
__global__ __launch_bounds__(512, 4) void fconv_k(
        const float* __restrict__ x, const short* __restrict__ wsp,
        const float* __restrict__ bias, const float2* __restrict__ stats,
        float* __restrict__ out, float2* __restrict__ part) {
    constexpr int NCH  = (C_IN + 31) / 32;
    constexpr int HALO = KS / 2;
    constexpr int TT   = 128;                    // t-tile
    constexpr int WT   = (KS == 1) ? 2 : 1;      // waves along t
    constexpr int WCO  = 8 / WT;                 // waves along co
    constexpr int HT   = TT / WT;                // t per wave
    constexpr int NTT  = HT / 16;                // MFMA t-subtiles per wave
    constexpr int NTILE = T_LEN / TT;
    constexpr int XR   = TT + KS - 1;
    constexpr int RS   = 72;                     // shorts/row (144B, 16B-aligned)
    constexpr int LO   = 40;                     // lo-plane offset within row
    constexpr int TQ   = TT / 4;                 // t-stride for 4-way load

    __shared__ __align__(16) short xs[2][XR * RS];

    const int tid  = threadIdx.x;
    const int lane = tid & 63;
    const int wv   = tid >> 6;
    const int wvc  = wv % WCO;                   // co strip
    const int wvt  = wv / WCO;                   // t half (KS==1 only)
    const int ln   = lane & 15;
    const int q    = lane >> 4;

    const int n    = blockIdx.x / NTILE;
    const int t0   = (blockIdx.x % NTILE) * TT;
    const int co0  = blockIdx.y * (WCO * 16);
    const int co_l = co0 + wvc * 16 + ln;        // A-fragment row for this lane

    // ---- staging helper: chunk c -> buf ----
    auto stage = [&](int c, short* buf) {
        for (int e = tid; e < 32 * TQ; e += 512) {
            const int ci  = e / TQ;
            const int tq  = e % TQ;
            const int cig = c * 32 + ci;
            float v[4] = {0.f, 0.f, 0.f, 0.f};
            if (cig < C_IN) {
                const float* xp = x + ((size_t)(n * C_IN + cig)) * T_LEN + t0 + tq;
#pragma unroll
                for (int j = 0; j < 4; ++j) v[j] = xp[TQ * j];
                if (BN_IN) {
                    float2 s = stats[cig];
#pragma unroll
                    for (int j = 0; j < 4; ++j) v[j] = fmaxf(fmaf(v[j], s.x, s.y), 0.f);
                }
            }
#pragma unroll
            for (int j = 0; j < 4; ++j) {
                short h, l; f2h2(v[j], h, l);
                short* p = &buf[(HALO + tq + TQ * j) * RS + ci];
                p[0]  = h;
                p[LO] = l;
            }
        }
        if (KS == 3) {
            if (tid < 64) {
                const int ci   = tid & 31;
                const int side = tid >> 5;
                const int cig  = c * 32 + ci;
                const int gt   = side ? (t0 + TT) : (t0 - 1);
                float v = 0.f;
                if (cig < C_IN && gt >= 0 && gt < T_LEN) {
                    v = x[((size_t)(n * C_IN + cig)) * T_LEN + gt];
                    if (BN_IN) {
                        float2 s = stats[cig];
                        v = fmaxf(fmaf(v, s.x, s.y), 0.f);
                    }
                }
                short h, l; f2h2(v, h, l);
                short* p = &buf[(side ? (XR - 1) : 0) * RS + ci];
                p[0] = h; p[LO] = l;
            }
        }
    };

    f32x4 a0[NTT], a1[NTT];
#pragma unroll
    for (int tt = 0; tt < NTT; ++tt)
#pragma unroll
        for (int i = 0; i < 4; ++i) { a0[tt][i] = 0.f; a1[tt][i] = 0.f; }

    // prologue: stage chunk 0
    stage(0, xs[0]);

#pragma unroll 1
    for (int c = 0; c < NCH; ++c) {
        // w fragments for this chunk (global, L2-hot; latency hides under stage)
        half8 ah[KS], al[KS];
        {
            half8 z = {0, 0, 0, 0, 0, 0, 0, 0};
#pragma unroll
            for (int k = 0; k < KS; ++k) {
                const short* wp = wsp
                    + ((size_t)(c * KS + k) * 2 * C_OUT + co_l) * 32 + q * 8;
                ah[k] = (co_l < C_OUT) ? *(const half8*)wp : z;
                al[k] = (co_l < C_OUT) ? *(const half8*)(wp + (size_t)C_OUT * 32) : z;
            }
        }

        __syncthreads();                  // buf[c&1] fully staged; prev reads done
        if (c + 1 < NCH) stage(c + 1, xs[(c + 1) & 1]);   // overlaps with MFMA

        const short* sb = xs[c & 1];
#pragma unroll
        for (int k = 0; k < KS; ++k) {
#pragma unroll
            for (int tt = 0; tt < NTT; ++tt) {
                const short* xr = &sb[(wvt * HT + tt * 16 + ln + k) * RS + q * 8];
                half8 bh = *(const half8*)&xr[0];
                half8 bl = *(const half8*)&xr[LO];
                a0[tt] = __builtin_amdgcn_mfma_f32_16x16x32_f16(ah[k], bh, a0[tt], 0, 0, 0);
                a1[tt] = __builtin_amdgcn_mfma_f32_16x16x32_f16(ah[k], bl, a1[tt], 0, 0, 0);
                a1[tt] = __builtin_amdgcn_mfma_f32_16x16x32_f16(al[k], bh, a1[tt], 0, 0, 0);
            }
        }
    }

    // epilogue: lane reg r -> D[co = co0+wvc*16+q*4+r][t = t0+wvt*HT+tt*16+ln]
    const int plinear = blockIdx.y * (N_B * NTILE) + blockIdx.x;
#pragma unroll
    for (int r = 0; r < 4; ++r) {
        const int co = co0 + wvc * 16 + q * 4 + r;
        float s1 = 0.f, s2 = 0.f;
        if (co < C_OUT) {
            const float bv = bias[co];
            float* op = out + ((size_t)(n * C_OUT + co)) * T_LEN + t0 + wvt * HT + ln;
#pragma unroll
            for (int tt = 0; tt < NTT; ++tt) {
                const float v = fmaf(a1[tt][r], 0.000244140625f, a0[tt][r]) + bv;
                op[tt * 16] = v;
                if (STATS) { s1 += v; s2 = fmaf(v, v, s2); }
            }
        }
        if (STATS) {
#pragma unroll
            for (int off = 1; off <= 8; off <<= 1) {
                s1 += __shfl_xor(s1, off);
                s2 += __shfl_xor(s2, off);
            }
            if (ln == 0)
                part[(size_t)plinear * 128 + wvc * 16 + q * 4 + r] =
                    make_float2(s1, s2);
        }
    }
}

// ---- BN stats: reduce 512 per-block float2 partials per channel (f64) ----
__global__ __launch_bounds__(256) void stats_k(
        const float2* __restrict__ part, const float* __restrict__ g,
        const float* __restrict__ b, float2* __restrict__ stats) {
    const int c = blockIdx.x;
    const int tid = threadIdx.x;
    double s1 = 0.0, s2 = 0.0;
    for (int j = tid; j < 512; j += 256) {
        float2 v = part[((size_t)(c >> 7) * 512 + j) * 128 + (c & 127)];
        s1 += (double)v.x; s2 += (double)v.y;
    }
    __shared__ double r1[256], r2[256];
    r1[tid] = s1; r2[tid] = s2;
    __syncthreads();
    for (int s = 128; s > 0; s >>= 1) {
        if (tid < s) { r1[tid] += r1[tid + s]; r2[tid] += r2[tid + s]; }
        __syncthreads();
    }
    if (tid == 0) {
        double m   = r1[0] / 65536.0;
        double var = r2[0] / 65536.0 - m * m;
        double sc  = (double)g[c] / sqrt(var + 1e-5);
        stats[c] = make_float2((float)sc, (float)((double)b[c] - m * sc));
    }
}

// ---- VQ via scaled-f16 split MFMA (16x16x32, r3/r8-proven, verbatim) ----
__global__ __launch_bounds__(256) void vq_k(
        const float* __restrict__ z, const float* __restrict__ cb,
        const short* __restrict__ cbs, const float* __restrict__ c2,
        float* __restrict__ q, float* __restrict__ idx_out,
        double* __restrict__ loss) {
    __shared__ __align__(16) float zs[64 * 68];
    __shared__ __align__(16) short zh[64 * 136];
    __shared__ float  c2s[512];
    __shared__ float  szf_s[64];
    __shared__ int    idxs[64];
    __shared__ double dred[256];

    const int tid  = threadIdx.x;
    const int lane = tid & 63;
    const int wv   = tid >> 6;
    const int ln   = lane & 15;
    const int q4   = lane >> 4;
    const int n    = blockIdx.x >> 6;
    const int t0   = (blockIdx.x & 63) * 64;

    for (int e = tid; e < 512; e += 256) c2s[e] = c2[e];
    for (int e = tid; e < 1024; e += 256) {
        const int d  = e >> 4;
        const int tq = e & 15;
        const float* zp = z + ((size_t)(n * 64 + d)) * T_LEN + t0 + tq;
        const int ks = d >> 5, i = d & 31;
#pragma unroll
        for (int j = 0; j < 4; ++j) {
            const int t = tq + 16 * j;
            float v = zp[16 * j];
            zs[t * 68 + d] = v;
            short h, l; f2h2(v, h, l);
            zh[t * 136 + (ks * 2 + 0) * 32 + i] = h;
            zh[t * 136 + (ks * 2 + 1) * 32 + i] = l;
        }
    }
    __syncthreads();
    if (tid < 64) {
        double s = 0.0;
        const float* zr = &zs[tid * 68];
        for (int d = 0; d < 64; ++d) { double v = zr[d]; s += v * v; }
        szf_s[tid] = (float)s;
    }
    __syncthreads();

    const short* zr = &zh[(wv * 16 + ln) * 136 + q4 * 8];
    const half8 bh0 = *(const half8*)&zr[0];
    const half8 bl0 = *(const half8*)&zr[32];
    const half8 bh1 = *(const half8*)&zr[64];
    const half8 bl1 = *(const half8*)&zr[96];
    const float As  = szf_s[wv * 16 + ln];

    float bs = 3.0e38f;
    int   bi = 1 << 30;

#pragma unroll 4
    for (int ct = 0; ct < 32; ++ct) {
        const short* ap = cbs + ((size_t)(ct * 16 + ln)) * 32 + q4 * 8;
        const half8 ah0 = *(const half8*)&ap[0];
        const half8 al0 = *(const half8*)&ap[512 * 32];
        const half8 ah1 = *(const half8*)&ap[2 * 512 * 32];
        const half8 al1 = *(const half8*)&ap[3 * 512 * 32];
        f32x4 a0 = {0.f, 0.f, 0.f, 0.f};
        f32x4 a1 = {0.f, 0.f, 0.f, 0.f};
        a0 = __builtin_amdgcn_mfma_f32_16x16x32_f16(ah0, bh0, a0, 0, 0, 0);
        a1 = __builtin_amdgcn_mfma_f32_16x16x32_f16(ah0, bl0, a1, 0, 0, 0);
        a1 = __builtin_amdgcn_mfma_f32_16x16x32_f16(al0, bh0, a1, 0, 0, 0);
        a0 = __builtin_amdgcn_mfma_f32_16x16x32_f16(ah1, bh1, a0, 0, 0, 0);
        a1 = __builtin_amdgcn_mfma_f32_16x16x32_f16(ah1, bl1, a1, 0, 0, 0);
        a1 = __builtin_amdgcn_mfma_f32_16x16x32_f16(al1, bh1, a1, 0, 0, 0);
#pragma unroll
        for (int r = 0; r < 4; ++r) {
            const int code = ct * 16 + q4 * 4 + r;
            const float m32 = fmaf(a1[r], 0.000244140625f, a0[r]);
            const float A   = As + c2s[code];
            const float s   = A - 2.0f * m32;
            if (s < bs || (s == bs && code < bi)) { bs = s; bi = code; }
        }
    }
#pragma unroll
    for (int off = 16; off <= 32; off <<= 1) {
        const float os = __shfl_xor(bs, off);
        const int   oi = __shfl_xor(bi, off);
        if (os < bs || (os == bs && oi < bi)) { bs = os; bi = oi; }
    }
    if (q4 == 0) {
        const int t = wv * 16 + ln;
        idxs[t] = bi;
        idx_out[(size_t)n * T_LEN + t0 + t] = (float)bi;
    }
    __syncthreads();

    {
        const int g = tid >> 6, t = tid & 63;
        const int bi2 = idxs[t];
        double ls = 0.0;
        for (int dd = 0; dd < 16; ++dd) {
            const int d = g * 16 + dd;
            const float qv = cb[(size_t)bi2 * 64 + d];
            const float zv = zs[t * 68 + d];
            const double df = (double)qv - (double)zv;
            ls += df * df;
            q[((size_t)(n * 64 + d)) * T_LEN + t0 + t] = qv;
        }
        dred[tid] = ls;
    }
    __syncthreads();
    for (int s = 128; s > 0; s >>= 1) {
        if (tid < s) dred[tid] += dred[tid + s];
        __syncthreads();
    }
    if (tid == 0) atomicAdd(loss, dred[0]);
}

__global__ void fin_k(const double* __restrict__ loss, float* __restrict__ out) {
    if (threadIdx.x == 0 && blockIdx.x == 0)
        out[0] = (float)(1.25 * (*loss) / 4194304.0);
}

extern "C" void kernel_launch(void* const* d_in, const int* in_sizes, int n_in,
                              void* d_out, int out_size, void* d_ws, size_t ws_size,
                              hipStream_t stream) {
    const float* x      = (const float*)d_in[0];
    const float* enc_w1 = (const float*)d_in[1];
    const float* enc_b1 = (const float*)d_in[2];
    const float* bn1_g  = (const float*)d_in[3];
    const float* bn1_b  = (const float*)d_in[4];
    const float* enc_w2 = (const float*)d_in[5];
    const float* enc_b2 = (const float*)d_in[6];
    const float* bn2_g  = (const float*)d_in[7];
    const float* bn2_b  = (const float*)d_in[8];
    const float* enc_w3 = (const float*)d_in[9];
    const float* enc_b3 = (const float*)d_in[10];
    const float* cb     = (const float*)d_in[11];
    const float* dec_w1 = (const float*)d_in[12];
    const float* dec_b1 = (const float*)d_in[13];
    const float* dbn1_g = (const float*)d_in[14];
    const float* dbn1_b = (const float*)d_in[15];
    const float* dec_w2 = (const float*)d_in[16];
    const float* dec_b2 = (const float*)d_in[17];
    const float* dbn2_g = (const float*)d_in[18];
    const float* dbn2_b = (const float*)d_in[19];
    const float* dec_w3 = (const float*)d_in[20];
    const float* dec_b3 = (const float*)d_in[21];

    float* wsf   = (float*)d_ws;
    float* outf  = (float*)d_out;
    float* A     = wsf + OFF_A;
    float* Bb    = wsf + OFF_B;
    float* Z     = wsf + OFF_Z;
    float2* st   = (float2*)(wsf + OFF_ST);
    double* lossp = (double*)(wsf + OFF_LOSS);

    const short* wsE1 = (const short*)(wsf + OFF_WS + WS_E1);
    const short* wsE2 = (const short*)(wsf + OFF_WS + WS_E2);
    const short* wsE3 = (const short*)(wsf + OFF_WS + WS_E3);
    const short* wsD1 = (const short*)(wsf + OFF_WS + WS_D1);
    const short* wsD2 = (const short*)(wsf + OFF_WS + WS_D2);
    const short* wsD3 = (const short*)(wsf + OFF_WS + WS_D3);
    const short* cbs  = (const short*)(wsf + OFF_CBS);

    // partial-stat buffers live in whichever big buffer is dead at that stage
    float2* pE1 = (float2*)Bb;   // enc1: Bb free until enc2 writes it
    float2* pE2 = (float2*)Z;    // enc2: Z free until enc3 writes it
    float2* pD1 = (float2*)A;    // dec1: A free until dec2 writes it
    float2* pD2 = (float2*)(wsf + OFF_B + 4194304); // dec2: upper half of Bb (dead)

    prep_k<<<723, 256, 0, stream>>>(enc_w1, enc_w2, enc_w3, cb, wsf);

    // encoder — 8-wave blocks, 2-phase pipelined staging
    fconv_k<80, 128, 3, false, true><<<dim3(512, 1), 512, 0, stream>>>(
        x, wsE1, enc_b1, nullptr, A, pE1);
    stats_k<<<128, 256, 0, stream>>>(pE1, bn1_g, bn1_b, st);
    fconv_k<128, 256, 3, true, true><<<dim3(512, 2), 512, 0, stream>>>(
        A, wsE2, enc_b2, st, Bb, pE2);
    stats_k<<<256, 256, 0, stream>>>(pE2, bn2_g, bn2_b, st);
    fconv_k<256, 64, 1, true, false><<<dim3(512, 1), 512, 0, stream>>>(
        Bb, wsE3, enc_b3, st, Z, nullptr);

    // decoder splits overwrite (now-dead) encoder splits
    prep2_k<<<696, 256, 0, stream>>>(dec_w1, dec_w2, dec_w3, wsf);

    // vector quantizer (q written in-place into Z)
    vq_k<<<1024, 256, 0, stream>>>(Z, cb, cbs, wsf + OFF_C2, Z,
                                   outf + 5242881, lossp);
    fin_k<<<1, 64, 0, stream>>>(lossp, outf + 5242880);

    // decoder
    fconv_k<64, 256, 3, false, true><<<dim3(512, 2), 512, 0, stream>>>(
        Z, wsD1, dec_b1, nullptr, Bb, pD1);
    stats_k<<<256, 256, 0, stream>>>(pD1, dbn1_g, dbn1_b, st);
    fconv_k<256, 128, 3, true, true><<<dim3(512, 1), 512, 0, stream>>>(
        Bb, wsD2, dec_b2, st, A, pD2);
    stats_k<<<128, 256, 0, stream>>>(pD2, dbn2_g, dbn2_b, st);
    fconv_k<128, 80, 3, true, false><<<dim3(512, 1), 512, 0, stream>>>(
        A, wsD3, dec_b3, st, outf, nullptr);
}